// Round 1
// baseline (461.275 us; speedup 1.0000x reference)
//
#include <hip/hip_runtime.h>
#include <hip/hip_bf16.h>

// B=8, R=8, N=1024, D_IN=D_OUT=256, all fp32 in/out.
// prep_w : Wt[r][e][d] = bf16(W[r][d][e])         (scratch: first 1 MB of d_out, pre-memset)
// stage 1: sup[b,r,e,n] = bf16(x@W + bias)         (ws, 32 MB)
// stage 2: out[b,m,e] += adj[b,r,m,n]*sup[b,r,e,n]  (bf16 MFMA, split-K=8, atomicAdd)
// stage 3: ReLU in place.
//
// R5: VGPR-staged bf16 tiles at pitch 40 (2-way banks = free; DMA staging forced 8/16-way
// conflicts). Double-buffered LDS with ONE barrier/iter; global loads issued AFTER the
// barrier so they overlap frag-reads+MFMA+next-stage instead of being drained by vmcnt(0).
// gemm grid: e2-pair blocks differ by 8 in linear index -> same XCD -> adj tile L2-shared.
//
// R6: __launch_bounds__(256,4) capped VGPRs at 128, but live demand in both MFMA kernels is
// ~135-145 (acc 64 + staging 20-24 + frag arrays 32 + addresses) -> inner-loop scratch
// spills (flat ops serialize vmcnt+lgkmcnt before every barrier + ~GiB scratch traffic).
// Relax to (256,3): 168-VGPR cap fits the demand spill-free; LDS (40 KiB/block) still
// allows the 3 blocks/CU we declare, preserving cross-block barrier-stall hiding.

#define Rr 8
#define Nn 1024
#define Dd 256
#define PITCH 40

typedef __attribute__((ext_vector_type(8))) short short8;
typedef __attribute__((ext_vector_type(4))) float f32x4;

__device__ __forceinline__ short f2bf(float f) {
    unsigned u = __builtin_bit_cast(unsigned, f);
    u += 0x7fffu + ((u >> 16) & 1u);   // RNE
    return (short)(u >> 16);
}

// ---------------- prep: Wt[r][e][d] bf16 <- W[r][d][e] f32 ----------------
__global__ void prep_w_kernel(const float* __restrict__ W, short* __restrict__ Wt) {
    __shared__ short T[64][72];
    const int tid = threadIdx.x;
    const int et = blockIdx.x, dt = blockIdx.y, r = blockIdx.z;
    const float* Wr = W + ((size_t)r * Dd + dt * 64) * Dd + et * 64;
    #pragma unroll
    for (int i = 0; i < 4; ++i) {
        int idx = tid + i * 256;
        int d_l = idx >> 4;
        int e4  = (idx & 15) * 4;
        f32x4 v = *(const f32x4*)(Wr + d_l * Dd + e4);
        T[e4 + 0][d_l] = f2bf(v[0]);
        T[e4 + 1][d_l] = f2bf(v[1]);
        T[e4 + 2][d_l] = f2bf(v[2]);
        T[e4 + 3][d_l] = f2bf(v[3]);
    }
    __syncthreads();
    short* o = Wt + ((size_t)r * Dd + et * 64) * Dd + dt * 64;
    #pragma unroll
    for (int i = 0; i < 2; ++i) {
        int idx = tid + i * 256;
        *(short8*)(o + (idx >> 3) * Dd + (idx & 7) * 8) = *(const short8*)&T[idx >> 3][(idx & 7) * 8];
    }
}

// ---------------- Stage 1: sup[b,r,e,n] = bf16(Wt @ x^T + bias) ----------------
// grid (2 e_t, 8 n_t, 64 br), block 256 = 4 waves (2e x 2n), tile 128e x 128n, BK=32, 8 iters.
__global__ __launch_bounds__(256, 3) void support_kernel(
        const float* __restrict__ x, const short* __restrict__ Wt,
        const float* __restrict__ bias, short* __restrict__ sup) {
    __shared__ short As[2][128 * PITCH];   // [e][d] bf16
    __shared__ short Bs[2][128 * PITCH];   // [n][d] bf16

    const int tid = threadIdx.x;
    const int wave = tid >> 6, lane = tid & 63;
    const int quad = lane >> 4, l16 = lane & 15;
    const int e_t = blockIdx.x, n_t = blockIdx.y, br = blockIdx.z;
    const int b = br >> 3, r = br & 7;
    const int we = wave & 1, wn = wave >> 1;

    const short* wp = Wt + ((size_t)r * Dd + e_t * 128) * Dd;
    const float* xb = x + ((size_t)b * Nn + n_t * 128) * Dd;

    short8 aw[2];
    f32x4 xv[4];
    auto gload = [&](int d0) {
        #pragma unroll
        for (int i = 0; i < 2; ++i) {
            int idx = tid + i * 256;
            aw[i] = *(const short8*)(wp + (idx >> 2) * Dd + d0 + (idx & 3) * 8);
        }
        #pragma unroll
        for (int i = 0; i < 2; ++i) {
            int idx = tid + i * 256;
            const float* p = xb + (idx >> 2) * Dd + d0 + (idx & 3) * 8;
            xv[2 * i]     = *(const f32x4*)p;
            xv[2 * i + 1] = *(const f32x4*)(p + 4);
        }
    };
    auto stage = [&](int buf) {
        #pragma unroll
        for (int i = 0; i < 2; ++i) {
            int idx = tid + i * 256;
            *(short8*)&As[buf][(idx >> 2) * PITCH + (idx & 3) * 8] = aw[i];
        }
        #pragma unroll
        for (int i = 0; i < 2; ++i) {
            int idx = tid + i * 256;
            short8 t;
            t[0] = f2bf(xv[2 * i][0]); t[1] = f2bf(xv[2 * i][1]);
            t[2] = f2bf(xv[2 * i][2]); t[3] = f2bf(xv[2 * i][3]);
            t[4] = f2bf(xv[2 * i + 1][0]); t[5] = f2bf(xv[2 * i + 1][1]);
            t[6] = f2bf(xv[2 * i + 1][2]); t[7] = f2bf(xv[2 * i + 1][3]);
            *(short8*)&Bs[buf][(idx >> 2) * PITCH + (idx & 3) * 8] = t;
        }
    };

    f32x4 acc[4][4] = {};
    gload(0);
    for (int it = 0; it < 8; ++it) {
        const int buf = it & 1;
        stage(buf);
        __syncthreads();
        if (it < 7) gload((it + 1) * 32);   // flies through frag reads + MFMA + next stage
        short8 a[4], bfr[4];
        #pragma unroll
        for (int i = 0; i < 4; ++i)
            a[i] = *(const short8*)&As[buf][(we * 64 + i * 16 + l16) * PITCH + quad * 8];
        #pragma unroll
        for (int j = 0; j < 4; ++j)
            bfr[j] = *(const short8*)&Bs[buf][(wn * 64 + j * 16 + l16) * PITCH + quad * 8];
        #pragma unroll
        for (int i = 0; i < 4; ++i)
            #pragma unroll
            for (int j = 0; j < 4; ++j)
                acc[i][j] = __builtin_amdgcn_mfma_f32_16x16x32_bf16(a[i], bfr[j], acc[i][j], 0, 0, 0);
    }

    // Epilogue: C[row=e][col=n]; add bias; bf16 store to sup[(b,r),e,n].
    #pragma unroll
    for (int i = 0; i < 4; ++i)
        #pragma unroll
        for (int reg = 0; reg < 4; ++reg) {
            int e = e_t * 128 + we * 64 + i * 16 + quad * 4 + reg;
            float bv = bias[r * Dd + e];
            #pragma unroll
            for (int j = 0; j < 4; ++j) {
                int n = n_t * 128 + wn * 64 + j * 16 + l16;
                sup[(((b * Rr + r) * Dd + e) << 10) + n] = f2bf(acc[i][j][reg] + bv);
            }
        }
}

// ---------------- Stage 2: out += adj @ sup^T (split-K=8) ----------------
// grid (16, 8, 8); bx: r = bx&7, e2 = bx>>3 -> e2-pairs differ by 8 -> same XCD (L2-share adj).
// block 256 = 4 waves (2m x 2e), tile 128m x 128e, BK=32, 32 iters.
__global__ __launch_bounds__(256, 3) void gcn_gemm_kernel(
        const float* __restrict__ adj, const short* __restrict__ sup,
        float* __restrict__ out) {
    __shared__ short Aa[2][128 * PITCH];   // [m][k] bf16 (cvt from fp32 adj)
    __shared__ short Bs[2][128 * PITCH];   // [e][k] bf16 (sup passthrough)

    const int tid = threadIdx.x;
    const int wave = tid >> 6, lane = tid & 63;
    const int quad = lane >> 4, l16 = lane & 15;
    const int r = blockIdx.x & 7, e2 = blockIdx.x >> 3;
    const int m_t = blockIdx.y, b = blockIdx.z;
    const int wm = wave >> 1, we = wave & 1;

    const float* ap = adj + ((size_t)((b * Rr + r) * Nn + m_t * 128)) * Nn;
    const short* bp = sup + (((size_t)((b * Rr + r) * Dd + e2 * 128)) << 10);

    f32x4 av[4];
    short8 bv[2];
    auto gload = [&](int kk) {
        #pragma unroll
        for (int i = 0; i < 2; ++i) {
            int idx = tid + i * 256;
            const float* p = ap + (size_t)(idx >> 2) * Nn + kk + (idx & 3) * 8;
            av[2 * i]     = *(const f32x4*)p;
            av[2 * i + 1] = *(const f32x4*)(p + 4);
        }
        #pragma unroll
        for (int i = 0; i < 2; ++i) {
            int idx = tid + i * 256;
            bv[i] = *(const short8*)(bp + ((size_t)(idx >> 2) << 10) + kk + (idx & 3) * 8);
        }
    };
    auto stage = [&](int buf) {
        #pragma unroll
        for (int i = 0; i < 2; ++i) {
            int idx = tid + i * 256;
            short8 t;
            t[0] = f2bf(av[2 * i][0]); t[1] = f2bf(av[2 * i][1]);
            t[2] = f2bf(av[2 * i][2]); t[3] = f2bf(av[2 * i][3]);
            t[4] = f2bf(av[2 * i + 1][0]); t[5] = f2bf(av[2 * i + 1][1]);
            t[6] = f2bf(av[2 * i + 1][2]); t[7] = f2bf(av[2 * i + 1][3]);
            *(short8*)&Aa[buf][(idx >> 2) * PITCH + (idx & 3) * 8] = t;
        }
        #pragma unroll
        for (int i = 0; i < 2; ++i) {
            int idx = tid + i * 256;
            *(short8*)&Bs[buf][(idx >> 2) * PITCH + (idx & 3) * 8] = bv[i];
        }
    };

    f32x4 acc[4][4] = {};
    gload(0);
    for (int it = 0; it < 32; ++it) {
        const int buf = it & 1;
        stage(buf);
        __syncthreads();
        if (it < 31) gload((it + 1) * 32);  // flies through frag reads + MFMA + next stage
        short8 a[4], bfr[4];
        #pragma unroll
        for (int i = 0; i < 4; ++i)
            a[i] = *(const short8*)&Aa[buf][(wm * 64 + i * 16 + l16) * PITCH + quad * 8];
        #pragma unroll
        for (int j = 0; j < 4; ++j)
            bfr[j] = *(const short8*)&Bs[buf][(we * 64 + j * 16 + l16) * PITCH + quad * 8];
        #pragma unroll
        for (int i = 0; i < 4; ++i)
            #pragma unroll
            for (int j = 0; j < 4; ++j)
                acc[i][j] = __builtin_amdgcn_mfma_f32_16x16x32_bf16(a[i], bfr[j], acc[i][j], 0, 0, 0);
    }

    // Epilogue: C[row=m][col=e]; split-K partial -> atomicAdd into zeroed out.
    float* ob = out + ((size_t)b * Nn + m_t * 128) * Dd + e2 * 128;
    #pragma unroll
    for (int i = 0; i < 4; ++i)
        #pragma unroll
        for (int reg = 0; reg < 4; ++reg) {
            int m_l = wm * 64 + i * 16 + quad * 4 + reg;
            #pragma unroll
            for (int j = 0; j < 4; ++j)
                atomicAdd(ob + (size_t)m_l * Dd + we * 64 + j * 16 + l16, acc[i][j][reg]);
        }
}

// ---------------- Stage 3: ReLU in place ----------------
__global__ void relu_kernel(float* __restrict__ out, int n4) {
    int i = blockIdx.x * blockDim.x + threadIdx.x;
    if (i < n4) {
        f32x4* p = (f32x4*)out;
        f32x4 v = p[i];
        v[0] = fmaxf(v[0], 0.f); v[1] = fmaxf(v[1], 0.f);
        v[2] = fmaxf(v[2], 0.f); v[3] = fmaxf(v[3], 0.f);
        p[i] = v;
    }
}

extern "C" void kernel_launch(void* const* d_in, const int* in_sizes, int n_in,
                              void* d_out, int out_size, void* d_ws, size_t ws_size,
                              hipStream_t stream) {
    const float* x    = (const float*)d_in[0];
    const float* adj  = (const float*)d_in[1];
    const float* W    = (const float*)d_in[2];
    const float* bias = (const float*)d_in[3];
    float* out = (float*)d_out;
    short* sup = (short*)d_ws;            // 32 MB of ws
    short* Wt  = (short*)d_out;           // 1 MB scratch inside d_out, consumed before memset

    prep_w_kernel<<<dim3(4, 4, 8), 256, 0, stream>>>(W, Wt);
    support_kernel<<<dim3(2, 8, 64), 256, 0, stream>>>(x, Wt, bias, sup);
    hipMemsetAsync(d_out, 0, (size_t)out_size * sizeof(float), stream);
    gcn_gemm_kernel<<<dim3(16, 8, 8), 256, 0, stream>>>(adj, sup, out);
    relu_kernel<<<(out_size / 4 + 255) / 256, 256, 0, stream>>>(out, out_size / 4);
}